// Round 11
// baseline (181.202 us; speedup 1.0000x reference)
//
#include <hip/hip_runtime.h>

typedef unsigned short u16;
typedef unsigned int u32;
typedef unsigned long long u64;
typedef __bf16 bf16x8 __attribute__((ext_vector_type(8)));
typedef float f32x4 __attribute__((ext_vector_type(4)));
typedef float f32x16 __attribute__((ext_vector_type(16)));

#define B_ 2
#define N_ 2048
#define C_ 768
#define H_ 12
#define M_ 4096  // B_*N_
#define SCALE_LOG2 0.18033688011112042f  // 0.125 * log2(e), folded into Q

// LDS map (odd strides: bank-group = (17*row + slot) mod 16 -> conflict-free b64)
#define KSTR 136
#define PSTR 72
#define K1OFF 8704    // 64*136
#define VOFF 17408
#define POFF 26112
#define PWSZ 2304     // 32*72 per wave
#define SMSZ 35328    // 26112 + 4*2304

static __device__ __forceinline__ u16 f2bf(float f) {
  u32 u = __builtin_bit_cast(u32, f);
  u32 r = u + 0x7fffu + ((u >> 16) & 1u);  // RNE
  return (u16)(r >> 16);
}
static __device__ __forceinline__ float fexp2(float x) {
#if __has_builtin(__builtin_amdgcn_exp2f)
  return __builtin_amdgcn_exp2f(x);
#else
  return __expf(x * 0.6931471805599453f);
#endif
}
static __device__ __forceinline__ u32 pack_bf16(float a, float b) {
  u32 r;
  asm("v_cvt_pk_bf16_f32 %0, %1, %2" : "=v"(r) : "v"(a), "v"(b));
  return r;
}
static __device__ __forceinline__ bf16x8 mk8(uint2 a, uint2 b) {
  uint4 u = make_uint4(a.x, a.y, b.x, b.y);
  return __builtin_bit_cast(bf16x8, u);
}

// async global->LDS, 16B per lane; LDS dest is wave-uniform base (HW adds lane*16)
static __device__ __forceinline__ void gload16(const void* g, void* lds_base) {
  __builtin_amdgcn_global_load_lds(
      (__attribute__((address_space(1))) void*)(u64)(g),
      (__attribute__((address_space(3))) void*)(u32)(u64)(lds_base), 16, 0, 0);
}

// ---------------- fp32 -> bf16 elementwise (x) ----------------
__global__ __launch_bounds__(256) void k_cvt4(const float* __restrict__ x,
                                              u16* __restrict__ xb, int n4) {
  int i = blockIdx.x * 256 + threadIdx.x;
  if (i >= n4) return;
  float4 v = ((const float4*)x)[i];
  ushort4 o;
  o.x = f2bf(v.x); o.y = f2bf(v.y); o.z = f2bf(v.z); o.w = f2bf(v.w);
  ((ushort4*)xb)[i] = o;
}

// ---------------- W[K][N] fp32 -> Wt[N][K] bf16, z selects (src, dst slab) ----------------
__global__ __launch_bounds__(256) void k_tconv2(const float* __restrict__ W0,
                                                const float* __restrict__ W1,
                                                u16* __restrict__ Wt, int K, int N) {
  const float* W = blockIdx.z ? W1 : W0;
  u16* dst = Wt + (u64)blockIdx.z * N * K;
  __shared__ float t[32][33];
  int n0 = blockIdx.x * 32, k0 = blockIdx.y * 32;
  int tx = threadIdx.x, ty = threadIdx.y;  // 32 x 8
#pragma unroll
  for (int i = 0; i < 4; i++)
    t[ty + i * 8][tx] = W[(u64)(k0 + ty + i * 8) * N + n0 + tx];
  __syncthreads();
#pragma unroll
  for (int i = 0; i < 4; i++)
    dst[(u64)(n0 + ty + i * 8) * K + k0 + tx] = f2bf(t[tx][ty + i * 8]);
}

// ---------------- fused QKV projection GEMM ----------------
__global__ __launch_bounds__(256) void k_gemm_qkv(const u16* __restrict__ A,
                                                  const u16* __restrict__ WQK,
                                                  const u16* __restrict__ WV,
                                                  u16* __restrict__ QKb,
                                                  u16* __restrict__ Vtout) {
  __shared__ u16 As[128 * 32];
  __shared__ u16 Bs[128 * 32];
  const int t = threadIdx.x;
  const int w = t >> 6, l = t & 63;
  const int wr = w >> 1, wc = w & 1;
  const int la = l & 15, lg = l >> 4;
  const int srow = l >> 2, scb = (l & 3) << 4;
  const int by = blockIdx.y;
  const bool isV = by >= 24;

  f32x4 acc[4][4];
#pragma unroll
  for (int i = 0; i < 4; i++)
#pragma unroll
    for (int j = 0; j < 4; j++) acc[i][j] = f32x4{0.f, 0.f, 0.f, 0.f};

  const u16* Ag = A + (u64)(blockIdx.x * 128) * 768;
  const u16* Bg = isV ? WV + (u64)((by - 24) * 128) * 768 : WQK + (u64)(by * 128) * 768;

  for (int k0 = 0; k0 < 768; k0 += 32) {
#pragma unroll
    for (int j = 0; j < 2; j++) {
      int r = (w * 2 + j) * 16 + srow;
      gload16((const char*)(Ag + (u64)r * 768 + k0) + scb, (char*)As + (w * 2 + j) * 1024);
      gload16((const char*)(Bg + (u64)r * 768 + k0) + scb, (char*)Bs + (w * 2 + j) * 1024);
    }
    __syncthreads();
    bf16x8 af[4], bfr[4];
#pragma unroll
    for (int m = 0; m < 4; m++)
      af[m] = *(const bf16x8*)(As + (wr * 64 + m * 16 + la) * 32 + lg * 8);
#pragma unroll
    for (int n = 0; n < 4; n++)
      bfr[n] = *(const bf16x8*)(Bs + (wc * 64 + n * 16 + la) * 32 + lg * 8);
#pragma unroll
    for (int m = 0; m < 4; m++)
#pragma unroll
      for (int n = 0; n < 4; n++)
        acc[m][n] =
            __builtin_amdgcn_mfma_f32_16x16x32_bf16(af[m], bfr[n], acc[m][n], 0, 0, 0);
    __syncthreads();
  }

#pragma unroll
  for (int m = 0; m < 4; m++) {
#pragma unroll
    for (int n = 0; n < 4; n++) {
      int grow0 = blockIdx.x * 128 + wr * 64 + m * 16 + lg * 4;
      if (!isV) {
        int gcol = by * 128 + wc * 64 + n * 16 + la;
        float sc = (gcol < 1536) ? SCALE_LOG2 : 1.0f;  // pre-scale Q columns
#pragma unroll
        for (int j = 0; j < 4; j++)
          QKb[(u64)(grow0 + j) * 3072 + gcol] = f2bf(acc[m][n][j] * sc);
      } else {
        int gcol = (by - 24) * 128 + wc * 64 + n * 16 + la;
        ushort4 o;
        o.x = f2bf(acc[m][n][0]); o.y = f2bf(acc[m][n][1]);
        o.z = f2bf(acc[m][n][2]); o.w = f2bf(acc[m][n][3]);
        *(ushort4*)(Vtout + (u64)gcol * M_ + grow0) = o;
      }
    }
  }
}

// ---------------- out-projection GEMM ----------------
__global__ __launch_bounds__(256) void k_gemm_out(const u16* __restrict__ A,
                                                  const u16* __restrict__ Bt,
                                                  float* __restrict__ Cout,
                                                  const float* __restrict__ bias) {
  __shared__ u16 As[128 * 32];
  __shared__ u16 Bs[128 * 32];
  const int t = threadIdx.x;
  const int w = t >> 6, l = t & 63;
  const int wr = w >> 1, wc = w & 1;
  const int la = l & 15, lg = l >> 4;
  const int srow = l >> 2, scb = (l & 3) << 4;

  f32x4 acc[4][4];
#pragma unroll
  for (int i = 0; i < 4; i++)
#pragma unroll
    for (int j = 0; j < 4; j++) acc[i][j] = f32x4{0.f, 0.f, 0.f, 0.f};

  const u16* Ag = A + (u64)(blockIdx.x * 128) * 768;
  const u16* Bg = Bt + (u64)(blockIdx.y * 128) * 768;

  for (int k0 = 0; k0 < 768; k0 += 32) {
#pragma unroll
    for (int j = 0; j < 2; j++) {
      int r = (w * 2 + j) * 16 + srow;
      gload16((const char*)(Ag + (u64)r * 768 + k0) + scb, (char*)As + (w * 2 + j) * 1024);
      gload16((const char*)(Bg + (u64)r * 768 + k0) + scb, (char*)Bs + (w * 2 + j) * 1024);
    }
    __syncthreads();
    bf16x8 af[4], bfr[4];
#pragma unroll
    for (int m = 0; m < 4; m++)
      af[m] = *(const bf16x8*)(As + (wr * 64 + m * 16 + la) * 32 + lg * 8);
#pragma unroll
    for (int n = 0; n < 4; n++)
      bfr[n] = *(const bf16x8*)(Bs + (wc * 64 + n * 16 + la) * 32 + lg * 8);
#pragma unroll
    for (int m = 0; m < 4; m++)
#pragma unroll
      for (int n = 0; n < 4; n++)
        acc[m][n] =
            __builtin_amdgcn_mfma_f32_16x16x32_bf16(af[m], bfr[n], acc[m][n], 0, 0, 0);
    __syncthreads();
  }

#pragma unroll
  for (int m = 0; m < 4; m++) {
#pragma unroll
    for (int n = 0; n < 4; n++) {
      int grow0 = blockIdx.x * 128 + wr * 64 + m * 16 + lg * 4;
      int gcol = blockIdx.y * 128 + wc * 64 + n * 16 + la;
      float bb = bias[gcol];
#pragma unroll
      for (int j = 0; j < 4; j++)
        Cout[(u64)(grow0 + j) * 768 + gcol] = acc[m][n][j] + bb;
    }
  }
}

// ---------------- fused dual-phase flash attention + combine (R7 template, 32-q blocks) ----
// Grid 1536 = 64 qt2 x 12 h x 2 b. 4 waves: w = p*2 + kvh; each wave computes the
// block's 32 q-rows x its 32-kv half of each 64-kv tile. Sync structure is the
// VERIFIED R7 sequence verbatim: vmcnt0 -> stage -> lgkm0 -> barrier -> prefetch ->
// compute -> barrier. Only per-wave work (one q-strip instead of two) changed.
__global__ __launch_bounds__(256, 4) void k_attn11(const u16* __restrict__ QKb,
                                                   const u16* __restrict__ Vt,
                                                   const float* __restrict__ lamp,
                                                   u16* __restrict__ Ob) {
  const int hw = blockIdx.x;
  const int wid = (hw & 7) * 192 + (hw >> 3);  // XCD-aware bijective swizzle (1536=8*192)
  const int qt2 = wid & 63;
  const int hb = wid >> 6;
  const int h = hb % H_, b = hb / H_;

  __shared__ __align__(16) char smem[SMSZ];
  const int t = threadIdx.x, w = t >> 6, l = t & 63;
  const int p = w >> 1, kvh = w & 1;
  const int ql = l & 31, hh = l >> 5;

  // Q B-frags: q = qt2*32 + ql, d = 16c + 8hh + j
  const u16* qrow =
      QKb + (u64)(b * N_ + qt2 * 32 + ql) * 3072 + p * 768 + h * 64 + hh * 8;
  bf16x8 qf[4];
#pragma unroll
  for (int c = 0; c < 4; c++) qf[c] = *(const bf16x8*)(qrow + 16 * c);

  f32x16 oacc[2];  // [d-half]
#pragma unroll
  for (int dh = 0; dh < 2; dh++)
#pragma unroll
    for (int r = 0; r < 16; r++) oacc[dh][r] = 0.f;
  float l_run = 0.f;

  // staging: thread covers rows rA and rA+32, 16B col-chunk cb (2 b64 each)
  const int rA = t >> 3, cb = (t & 7) << 4;
  const char* kg = (const char*)(QKb + (u64)(b * N_ + rA) * 3072 + 1536 + h * 64) + cb;
  const char* vg = (const char*)(Vt + (u64)(h * 64 + rA) * M_ + b * N_) + cb;
  const u64 KR32 = (u64)32 * 3072 * 2;
  const u64 VR32 = (u64)32 * M_ * 2;
  const u64 KSTEP = (u64)64 * 3072 * 2;
  char* d0a = smem + rA * KSTR + cb;
  char* d0b = smem + (rA + 32) * KSTR + cb;

  uint4 rk0A, rk0B, rk1A, rk1B, rvA, rvB;
#define LOADS6()                              \
  do {                                        \
    rk0A = *(const uint4*)(kg);               \
    rk0B = *(const uint4*)(kg + KR32);        \
    rk1A = *(const uint4*)(kg + 1536);        \
    rk1B = *(const uint4*)(kg + 1536 + KR32); \
    rvA = *(const uint4*)(vg);                \
    rvB = *(const uint4*)(vg + VR32);         \
  } while (0)
  LOADS6();

  // per-wave LDS read bases (static across kt)
  const char* kbase = smem + p * K1OFF + (32 * kvh + ql) * KSTR + 16 * hh;
  const char* vb0 = smem + VOFF + ql * KSTR + 64 * kvh + 16 * hh;
  const char* vb1 = smem + VOFF + (32 + ql) * KSTR + 64 * kvh + 16 * hh;
  char* pb = smem + POFF + w * PWSZ;
  char* pwr = pb + ql * PSTR + 8 * hh;
  const char* prd = pb + ql * PSTR + 16 * hh;

  for (int kt = 0; kt < 32; kt++) {
    asm volatile("s_waitcnt vmcnt(0)" ::: "memory");
    __builtin_amdgcn_sched_barrier(0);
    // stage K (both phases) + V: 12 ds_write_b64, plain offsets (stride-136 rows)
    *(uint2*)(d0a) = make_uint2(rk0A.x, rk0A.y);
    *(uint2*)(d0a + 8) = make_uint2(rk0A.z, rk0A.w);
    *(uint2*)(d0b) = make_uint2(rk0B.x, rk0B.y);
    *(uint2*)(d0b + 8) = make_uint2(rk0B.z, rk0B.w);
    *(uint2*)(d0a + K1OFF) = make_uint2(rk1A.x, rk1A.y);
    *(uint2*)(d0a + K1OFF + 8) = make_uint2(rk1A.z, rk1A.w);
    *(uint2*)(d0b + K1OFF) = make_uint2(rk1B.x, rk1B.y);
    *(uint2*)(d0b + K1OFF + 8) = make_uint2(rk1B.z, rk1B.w);
    *(uint2*)(d0a + VOFF) = make_uint2(rvA.x, rvA.y);
    *(uint2*)(d0a + VOFF + 8) = make_uint2(rvA.z, rvA.w);
    *(uint2*)(d0b + VOFF) = make_uint2(rvB.x, rvB.y);
    *(uint2*)(d0b + VOFF + 8) = make_uint2(rvB.z, rvB.w);
    asm volatile("s_waitcnt lgkmcnt(0)" ::: "memory");
    __builtin_amdgcn_s_barrier();
    kg += KSTEP;
    vg += 128;
    if (kt < 31) LOADS6();  // prefetch next tile; lands during compute
    __builtin_amdgcn_sched_barrier(0);

    // K fragments (wave's kv-half)
    bf16x8 kf[4];
#pragma unroll
    for (int c = 0; c < 4; c++)
      kf[c] = mk8(*(const uint2*)(kbase + 32 * c), *(const uint2*)(kbase + 32 * c + 8));
    // V fragments (wave's kv-half)
    bf16x8 vf[2][2];
#pragma unroll
    for (int dh = 0; dh < 2; dh++) {
      const char* vb = dh ? vb1 : vb0;
#pragma unroll
      for (int c2 = 0; c2 < 2; c2++)
        vf[dh][c2] =
            mk8(*(const uint2*)(vb + 32 * c2), *(const uint2*)(vb + 32 * c2 + 8));
    }

    // QK^T (swapped): S[kv' 32][q 32], kv' local to this wave's half
    f32x16 st;
#pragma unroll
    for (int r = 0; r < 16; r++) st[r] = 0.f;
    __builtin_amdgcn_s_setprio(1);
#pragma unroll
    for (int c = 0; c < 4; c++)
      st = __builtin_amdgcn_mfma_f32_32x32x16_bf16(kf[c], qf[c], st, 0, 0, 0);
    __builtin_amdgcn_s_setprio(0);

    // static-max softmax: P = exp2(S), partial l
    float sm[16];
#pragma unroll
    for (int r = 0; r < 16; r++) {
      st[r] = fexp2(st[r]);
      sm[r] = st[r];
    }
#pragma unroll
    for (int sd = 8; sd >= 1; sd >>= 1)
#pragma unroll
      for (int r = 0; r < sd; r++) sm[r] += sm[r + sd];
    l_run += sm[0] + __shfl_xor(sm[0], 32, 64);

    // P -> wave-private LDS (row=q stride 72; st[r]=P[q=ql][kv'=(r&3)+8(r>>2)+4hh])
#pragma unroll
    for (int g = 0; g < 4; g++) {
      uint2 pk;
      pk.x = pack_bf16(st[4 * g + 0], st[4 * g + 1]);
      pk.y = pack_bf16(st[4 * g + 2], st[4 * g + 3]);
      *(uint2*)(pwr + 16 * g) = pk;
    }
    // PV A-frags back (contiguous kv' convention, same as V)
    bf16x8 pa[2];
#pragma unroll
    for (int c2 = 0; c2 < 2; c2++)
      pa[c2] = mk8(*(const uint2*)(prd + 32 * c2), *(const uint2*)(prd + 32 * c2 + 8));

    __builtin_amdgcn_s_setprio(1);
#pragma unroll
    for (int c2 = 0; c2 < 2; c2++)
#pragma unroll
      for (int dh = 0; dh < 2; dh++)
        oacc[dh] = __builtin_amdgcn_mfma_f32_32x32x16_bf16(pa[c2], vf[dh][c2],
                                                           oacc[dh], 0, 0, 0);
    __builtin_amdgcn_s_setprio(0);
    __builtin_amdgcn_s_barrier();
  }

  // ---- epilogue: reduce over kvh, then combine phases ----
  float* Os = (float*)smem;             // [2][32][64] f32 = 16KB
  float* lsc = (float*)(smem + 16384);  // [2][32]
  __syncthreads();
  if (kvh == 1) {
#pragma unroll
    for (int dh = 0; dh < 2; dh++)
#pragma unroll
      for (int r = 0; r < 16; r++) {
        int qm = (r & 3) + 8 * (r >> 2) + 4 * hh;
        Os[(p * 32 + qm) * 64 + dh * 32 + ql] = oacc[dh][r];
      }
    lsc[p * 32 + ql] = l_run;
  }
  __syncthreads();
  if (kvh == 0) {
#pragma unroll
    for (int dh = 0; dh < 2; dh++)
#pragma unroll
      for (int r = 0; r < 16; r++) {
        int qm = (r & 3) + 8 * (r >> 2) + 4 * hh;
        oacc[dh][r] += Os[(p * 32 + qm) * 64 + dh * 32 + ql];
      }
    l_run += lsc[p * 32 + ql];
  }
  __syncthreads();
  if (kvh == 0 && p == 1) {
    float lam = __expf(lamp[h]);
    float inv = lam / l_run;
#pragma unroll
    for (int dh = 0; dh < 2; dh++)
#pragma unroll
      for (int r = 0; r < 16; r++) {
        int qm = (r & 3) + 8 * (r >> 2) + 4 * hh;
        float iT = __shfl(inv, qm, 64);
        Os[(32 + qm) * 64 + dh * 32 + ql] = oacc[dh][r] * iT;
      }
  }
  __syncthreads();
  if (kvh == 0 && p == 0) {
    float inv = 1.f / l_run;
    u16* Og = Ob + (u64)(b * N_ + qt2 * 32) * C_ + h * 64;
#pragma unroll
    for (int dh = 0; dh < 2; dh++)
#pragma unroll
      for (int r = 0; r < 16; r++) {
        int qm = (r & 3) + 8 * (r >> 2) + 4 * hh;
        float iT = __shfl(inv, qm, 64);
        int d = dh * 32 + ql;
        float v = oacc[dh][r] * iT - Os[(32 + qm) * 64 + d];
        Og[(u64)qm * C_ + d] = f2bf(v);
      }
  }
}

extern "C" void kernel_launch(void* const* d_in, const int* in_sizes, int n_in,
                              void* d_out, int out_size, void* d_ws, size_t ws_size,
                              hipStream_t stream) {
  const float* x = (const float*)d_in[0];
  const float* Wq = (const float*)d_in[1];
  const float* Wk = (const float*)d_in[2];
  const float* Wv = (const float*)d_in[3];
  const float* lamp = (const float*)d_in[4];
  const float* Wo = (const float*)d_in[5];
  const float* bo = (const float*)d_in[6];

  char* ws = (char*)d_ws;
  u16* xb = (u16*)ws;    ws += (u64)M_ * C_ * 2;       // x bf16 [4096][768]
  u16* wqkt = (u16*)ws;  ws += (u64)4 * C_ * C_ * 2;   // [Wq^T;Wk^T] [3072][768]
  u16* wvo = (u16*)ws;   ws += (u64)2 * C_ * C_ * 2;   // [Wv^T;Wo^T] [1536][768]
  u16* QKb = (u16*)ws;   ws += (u64)M_ * 4 * C_ * 2;   // [4096][3072]
  u16* Vt = (u16*)ws;    ws += (u64)C_ * M_ * 2;       // V^T [768][4096]
  u16* Ob = (u16*)ws;    ws += (u64)M_ * C_ * 2;       // combined [4096][768]
  u16* wvt = wvo;
  u16* wot = wvo + (u64)C_ * C_;

  k_cvt4<<<dim3(M_ * C_ / 4 / 256), 256, 0, stream>>>(x, xb, M_ * C_ / 4);
  k_tconv2<<<dim3(48, 24, 2), dim3(32, 8), 0, stream>>>(Wq, Wk, wqkt, 768, 1536);
  k_tconv2<<<dim3(24, 24, 2), dim3(32, 8), 0, stream>>>(Wv, Wo, wvo, 768, 768);
  k_gemm_qkv<<<dim3(32, 30), 256, 0, stream>>>(xb, wqkt, wvt, QKb, Vt);
  k_attn11<<<dim3(1536), 256, 0, stream>>>(QKb, Vt, lamp, Ob);
  k_gemm_out<<<dim3(32, 6), 256, 0, stream>>>(Ob, wot, (float*)d_out, bo);
}

// Round 12
// 145.040 us; speedup vs baseline: 1.2493x; 1.2493x over previous
//
#include <hip/hip_runtime.h>

typedef unsigned short u16;
typedef unsigned int u32;
typedef unsigned long long u64;
typedef __bf16 bf16x8 __attribute__((ext_vector_type(8)));
typedef float f32x4 __attribute__((ext_vector_type(4)));
typedef float f32x16 __attribute__((ext_vector_type(16)));

#define B_ 2
#define N_ 2048
#define C_ 768
#define H_ 12
#define M_ 4096  // B_*N_
#define SCALE_LOG2 0.18033688011112042f  // 0.125 * log2(e), folded into Q

// LDS map for k_attn (odd strides: bank-group = (17*row + slot) mod 16 -> conflict-free b64)
#define KSTR 136
#define PSTR 72
#define K1OFF 8704    // 64*136
#define VOFF 17408
#define POFF 26112
#define PWSZ 2304     // 32*72
#define SMSZ 35328

static __device__ __forceinline__ u16 f2bf(float f) {
  u32 u = __builtin_bit_cast(u32, f);
  u32 r = u + 0x7fffu + ((u >> 16) & 1u);  // RNE
  return (u16)(r >> 16);
}
static __device__ __forceinline__ float fexp2(float x) {
#if __has_builtin(__builtin_amdgcn_exp2f)
  return __builtin_amdgcn_exp2f(x);
#else
  return __expf(x * 0.6931471805599453f);
#endif
}
static __device__ __forceinline__ u32 pack_bf16(float a, float b) {
  u32 r;
  asm("v_cvt_pk_bf16_f32 %0, %1, %2" : "=v"(r) : "v"(a), "v"(b));
  return r;
}
static __device__ __forceinline__ bf16x8 mk8(uint2 a, uint2 b) {
  uint4 u = make_uint4(a.x, a.y, b.x, b.y);
  return __builtin_bit_cast(bf16x8, u);
}

// async global->LDS, 16B per lane; LDS dest is wave-uniform base (HW adds lane*16)
static __device__ __forceinline__ void gload16(const void* g, void* lds_base) {
  __builtin_amdgcn_global_load_lds(
      (__attribute__((address_space(1))) void*)(u64)(g),
      (__attribute__((address_space(3))) void*)(u32)(u64)(lds_base), 16, 0, 0);
}

// ---------------- fused prep: x cvt + Wq/Wk transpose + Wv/Wo transpose ----------------
// blockIdx.x partition: [0,3072) cvt x; [3072,5376) tconv QK; [5376,6528) tconv VO.
__global__ __launch_bounds__(256) void k_prep(const float* __restrict__ x,
                                              const float* __restrict__ Wq,
                                              const float* __restrict__ Wk,
                                              const float* __restrict__ Wv,
                                              const float* __restrict__ Wo,
                                              u16* __restrict__ xb,
                                              u16* __restrict__ wqkt,
                                              u16* __restrict__ wvo) {
  const int id = blockIdx.x;
  const int t = threadIdx.x;
  if (id < 3072) {  // ---- cvt: x fp32 -> bf16, 4 elems/thread ----
    int i = id * 256 + t;
    float4 v = ((const float4*)x)[i];
    ushort4 o;
    o.x = f2bf(v.x); o.y = f2bf(v.y); o.z = f2bf(v.z); o.w = f2bf(v.w);
    ((ushort4*)xb)[i] = o;
    return;
  }
  // ---- transpose-convert W[K=768][N] -> Wt[N][768] bf16 ----
  __shared__ float tt[32][33];
  const float* W;
  u16* dst;
  int bx, by;
  if (id < 5376) {  // QK: N=1536, 48x24 blocks, z in {0,1}
    int rem = id - 3072;
    int z = rem / 1152, r2 = rem % 1152;
    bx = r2 % 48; by = r2 / 48;
    W = z ? Wk : Wq;
    dst = wqkt + (u64)z * 1536 * 768;
    const int N = 1536;
    int n0 = bx * 32, k0 = by * 32;
    int tx = t & 31, ty = t >> 5;
#pragma unroll
    for (int i = 0; i < 4; i++)
      tt[ty + i * 8][tx] = W[(u64)(k0 + ty + i * 8) * N + n0 + tx];
    __syncthreads();
#pragma unroll
    for (int i = 0; i < 4; i++)
      dst[(u64)(n0 + ty + i * 8) * 768 + k0 + tx] = f2bf(tt[tx][ty + i * 8]);
  } else {  // VO: N=768, 24x24 blocks, z in {0,1}
    int rem = id - 5376;
    int z = rem / 576, r3 = rem % 576;
    bx = r3 % 24; by = r3 / 24;
    W = z ? Wo : Wv;
    dst = wvo + (u64)z * 768 * 768;
    const int N = 768;
    int n0 = bx * 32, k0 = by * 32;
    int tx = t & 31, ty = t >> 5;
#pragma unroll
    for (int i = 0; i < 4; i++)
      tt[ty + i * 8][tx] = W[(u64)(k0 + ty + i * 8) * N + n0 + tx];
    __syncthreads();
#pragma unroll
    for (int i = 0; i < 4; i++)
      dst[(u64)(n0 + ty + i * 8) * 768 + k0 + tx] = f2bf(tt[tx][ty + i * 8]);
  }
}

// ---------------- fused QKV projection GEMM ----------------
__global__ __launch_bounds__(256) void k_gemm_qkv(const u16* __restrict__ A,
                                                  const u16* __restrict__ WQK,
                                                  const u16* __restrict__ WV,
                                                  u16* __restrict__ QKb,
                                                  u16* __restrict__ Vtout) {
  __shared__ u16 As[128 * 32];
  __shared__ u16 Bs[128 * 32];
  const int t = threadIdx.x;
  const int w = t >> 6, l = t & 63;
  const int wr = w >> 1, wc = w & 1;
  const int la = l & 15, lg = l >> 4;
  const int srow = l >> 2, scb = (l & 3) << 4;
  const int by = blockIdx.y;
  const bool isV = by >= 24;

  f32x4 acc[4][4];
#pragma unroll
  for (int i = 0; i < 4; i++)
#pragma unroll
    for (int j = 0; j < 4; j++) acc[i][j] = f32x4{0.f, 0.f, 0.f, 0.f};

  const u16* Ag = A + (u64)(blockIdx.x * 128) * 768;
  const u16* Bg = isV ? WV + (u64)((by - 24) * 128) * 768 : WQK + (u64)(by * 128) * 768;

  for (int k0 = 0; k0 < 768; k0 += 32) {
#pragma unroll
    for (int j = 0; j < 2; j++) {
      int r = (w * 2 + j) * 16 + srow;
      gload16((const char*)(Ag + (u64)r * 768 + k0) + scb, (char*)As + (w * 2 + j) * 1024);
      gload16((const char*)(Bg + (u64)r * 768 + k0) + scb, (char*)Bs + (w * 2 + j) * 1024);
    }
    __syncthreads();
    bf16x8 af[4], bfr[4];
#pragma unroll
    for (int m = 0; m < 4; m++)
      af[m] = *(const bf16x8*)(As + (wr * 64 + m * 16 + la) * 32 + lg * 8);
#pragma unroll
    for (int n = 0; n < 4; n++)
      bfr[n] = *(const bf16x8*)(Bs + (wc * 64 + n * 16 + la) * 32 + lg * 8);
#pragma unroll
    for (int m = 0; m < 4; m++)
#pragma unroll
      for (int n = 0; n < 4; n++)
        acc[m][n] =
            __builtin_amdgcn_mfma_f32_16x16x32_bf16(af[m], bfr[n], acc[m][n], 0, 0, 0);
    __syncthreads();
  }

#pragma unroll
  for (int m = 0; m < 4; m++) {
#pragma unroll
    for (int n = 0; n < 4; n++) {
      int grow0 = blockIdx.x * 128 + wr * 64 + m * 16 + lg * 4;
      if (!isV) {
        int gcol = by * 128 + wc * 64 + n * 16 + la;
        float sc = (gcol < 1536) ? SCALE_LOG2 : 1.0f;  // pre-scale Q columns
#pragma unroll
        for (int j = 0; j < 4; j++)
          QKb[(u64)(grow0 + j) * 3072 + gcol] = f2bf(acc[m][n][j] * sc);
      } else {
        int gcol = (by - 24) * 128 + wc * 64 + n * 16 + la;
        ushort4 o;
        o.x = f2bf(acc[m][n][0]); o.y = f2bf(acc[m][n][1]);
        o.z = f2bf(acc[m][n][2]); o.w = f2bf(acc[m][n][3]);
        *(ushort4*)(Vtout + (u64)gcol * M_ + grow0) = o;
      }
    }
  }
}

// ---------------- out-projection GEMM ----------------
__global__ __launch_bounds__(256) void k_gemm_out(const u16* __restrict__ A,
                                                  const u16* __restrict__ Bt,
                                                  float* __restrict__ Cout,
                                                  const float* __restrict__ bias) {
  __shared__ u16 As[128 * 32];
  __shared__ u16 Bs[128 * 32];
  const int t = threadIdx.x;
  const int w = t >> 6, l = t & 63;
  const int wr = w >> 1, wc = w & 1;
  const int la = l & 15, lg = l >> 4;
  const int srow = l >> 2, scb = (l & 3) << 4;

  f32x4 acc[4][4];
#pragma unroll
  for (int i = 0; i < 4; i++)
#pragma unroll
    for (int j = 0; j < 4; j++) acc[i][j] = f32x4{0.f, 0.f, 0.f, 0.f};

  const u16* Ag = A + (u64)(blockIdx.x * 128) * 768;
  const u16* Bg = Bt + (u64)(blockIdx.y * 128) * 768;

  for (int k0 = 0; k0 < 768; k0 += 32) {
#pragma unroll
    for (int j = 0; j < 2; j++) {
      int r = (w * 2 + j) * 16 + srow;
      gload16((const char*)(Ag + (u64)r * 768 + k0) + scb, (char*)As + (w * 2 + j) * 1024);
      gload16((const char*)(Bg + (u64)r * 768 + k0) + scb, (char*)Bs + (w * 2 + j) * 1024);
    }
    __syncthreads();
    bf16x8 af[4], bfr[4];
#pragma unroll
    for (int m = 0; m < 4; m++)
      af[m] = *(const bf16x8*)(As + (wr * 64 + m * 16 + la) * 32 + lg * 8);
#pragma unroll
    for (int n = 0; n < 4; n++)
      bfr[n] = *(const bf16x8*)(Bs + (wc * 64 + n * 16 + la) * 32 + lg * 8);
#pragma unroll
    for (int m = 0; m < 4; m++)
#pragma unroll
      for (int n = 0; n < 4; n++)
        acc[m][n] =
            __builtin_amdgcn_mfma_f32_16x16x32_bf16(af[m], bfr[n], acc[m][n], 0, 0, 0);
    __syncthreads();
  }

#pragma unroll
  for (int m = 0; m < 4; m++) {
#pragma unroll
    for (int n = 0; n < 4; n++) {
      int grow0 = blockIdx.x * 128 + wr * 64 + m * 16 + lg * 4;
      int gcol = blockIdx.y * 128 + wc * 64 + n * 16 + la;
      float bb = bias[gcol];
#pragma unroll
      for (int j = 0; j < 4; j++)
        Cout[(u64)(grow0 + j) * 768 + gcol] = acc[m][n][j] + bb;
    }
  }
}

// ---------------- fused dual-phase flash attention + combine (R7 VERBATIM, verified 2x) ----
// 4 waves: w = p*2 + kvh  (p = phase, kvh = kv-half). Each wave: BOTH q-strips
// (64 q-rows) x its 32-kv half. Static-max softmax (partials summable over kvh).
// K/V LDS rows stride 136B, P stride 72B, all ds ops b64 -> ~conflict-free.
__global__ __launch_bounds__(256, 2) void k_attn7(const u16* __restrict__ QKb,
                                                  const u16* __restrict__ Vt,
                                                  const float* __restrict__ lamp,
                                                  u16* __restrict__ Ob) {
  const int hw = blockIdx.x;
  const int wid = (hw & 7) * 96 + (hw >> 3);  // XCD-aware bijective swizzle
  const int qt = wid & 31;
  const int hb = wid >> 5;
  const int h = hb % H_, b = hb / H_;

  __shared__ __align__(16) char smem[SMSZ];
  const int t = threadIdx.x, w = t >> 6, l = t & 63;
  const int p = w >> 1, kvh = w & 1;
  const int ql = l & 31, hh = l >> 5;

  // Q B-frags, both strips: q = qt*64 + s*32 + ql, d = 16c + 8hh + j
  bf16x8 qf[2][4];
#pragma unroll
  for (int s = 0; s < 2; s++) {
    const u16* qrow =
        QKb + (u64)(b * N_ + qt * 64 + s * 32 + ql) * 3072 + p * 768 + h * 64 + hh * 8;
#pragma unroll
    for (int c = 0; c < 4; c++) qf[s][c] = *(const bf16x8*)(qrow + 16 * c);
  }

  f32x16 oacc[2][2];  // [strip][d-half]
#pragma unroll
  for (int s = 0; s < 2; s++)
#pragma unroll
    for (int dh = 0; dh < 2; dh++)
#pragma unroll
      for (int r = 0; r < 16; r++) oacc[s][dh][r] = 0.f;
  float l_run[2] = {0.f, 0.f};

  // staging: thread covers rows rA and rA+32, 16B col-chunk cb (2 b64 each)
  const int rA = t >> 3, cb = (t & 7) << 4;
  const char* kg = (const char*)(QKb + (u64)(b * N_ + rA) * 3072 + 1536 + h * 64) + cb;
  const char* vg = (const char*)(Vt + (u64)(h * 64 + rA) * M_ + b * N_) + cb;
  const u64 KR32 = (u64)32 * 3072 * 2;
  const u64 VR32 = (u64)32 * M_ * 2;
  const u64 KSTEP = (u64)64 * 3072 * 2;
  char* d0a = smem + rA * KSTR + cb;
  char* d0b = smem + (rA + 32) * KSTR + cb;

  uint4 rk0A, rk0B, rk1A, rk1B, rvA, rvB;
#define LOADS6()                              \
  do {                                        \
    rk0A = *(const uint4*)(kg);               \
    rk0B = *(const uint4*)(kg + KR32);        \
    rk1A = *(const uint4*)(kg + 1536);        \
    rk1B = *(const uint4*)(kg + 1536 + KR32); \
    rvA = *(const uint4*)(vg);                \
    rvB = *(const uint4*)(vg + VR32);         \
  } while (0)
  LOADS6();

  // per-wave LDS read bases (static across kt)
  const char* kbase = smem + p * K1OFF + (32 * kvh + ql) * KSTR + 16 * hh;
  const char* vb0 = smem + VOFF + ql * KSTR + 64 * kvh + 16 * hh;
  const char* vb1 = smem + VOFF + (32 + ql) * KSTR + 64 * kvh + 16 * hh;
  char* pb = smem + POFF + w * PWSZ;
  char* pwr = pb + ql * PSTR + 8 * hh;
  const char* prd = pb + ql * PSTR + 16 * hh;

  for (int kt = 0; kt < 32; kt++) {
    asm volatile("s_waitcnt vmcnt(0)" ::: "memory");
    __builtin_amdgcn_sched_barrier(0);
    // stage K (both phases) + V: 12 ds_write_b64, plain offsets (stride-136 rows)
    *(uint2*)(d0a) = make_uint2(rk0A.x, rk0A.y);
    *(uint2*)(d0a + 8) = make_uint2(rk0A.z, rk0A.w);
    *(uint2*)(d0b) = make_uint2(rk0B.x, rk0B.y);
    *(uint2*)(d0b + 8) = make_uint2(rk0B.z, rk0B.w);
    *(uint2*)(d0a + K1OFF) = make_uint2(rk1A.x, rk1A.y);
    *(uint2*)(d0a + K1OFF + 8) = make_uint2(rk1A.z, rk1A.w);
    *(uint2*)(d0b + K1OFF) = make_uint2(rk1B.x, rk1B.y);
    *(uint2*)(d0b + K1OFF + 8) = make_uint2(rk1B.z, rk1B.w);
    *(uint2*)(d0a + VOFF) = make_uint2(rvA.x, rvA.y);
    *(uint2*)(d0a + VOFF + 8) = make_uint2(rvA.z, rvA.w);
    *(uint2*)(d0b + VOFF) = make_uint2(rvB.x, rvB.y);
    *(uint2*)(d0b + VOFF + 8) = make_uint2(rvB.z, rvB.w);
    asm volatile("s_waitcnt lgkmcnt(0)" ::: "memory");
    __builtin_amdgcn_s_barrier();
    kg += KSTEP;
    vg += 128;
    if (kt < 31) LOADS6();  // prefetch next tile; lands during compute
    __builtin_amdgcn_sched_barrier(0);

    // K fragments (wave's kv-half; shared by both strips)
    bf16x8 kf[4];
#pragma unroll
    for (int c = 0; c < 4; c++)
      kf[c] = mk8(*(const uint2*)(kbase + 32 * c), *(const uint2*)(kbase + 32 * c + 8));
    // V fragments (wave's kv-half; shared by both strips)
    bf16x8 vf[2][2];
#pragma unroll
    for (int dh = 0; dh < 2; dh++) {
      const char* vb = dh ? vb1 : vb0;
#pragma unroll
      for (int c2 = 0; c2 < 2; c2++)
        vf[dh][c2] =
            mk8(*(const uint2*)(vb + 32 * c2), *(const uint2*)(vb + 32 * c2 + 8));
    }

#pragma unroll
    for (int s = 0; s < 2; s++) {
      // QK^T (swapped): S[kv' 32][q 32], kv' local to this wave's half
      f32x16 st;
#pragma unroll
      for (int r = 0; r < 16; r++) st[r] = 0.f;
      __builtin_amdgcn_s_setprio(1);
#pragma unroll
      for (int c = 0; c < 4; c++)
        st = __builtin_amdgcn_mfma_f32_32x32x16_bf16(kf[c], qf[s][c], st, 0, 0, 0);
      __builtin_amdgcn_s_setprio(0);

      // static-max softmax: P = exp2(S), partial l
      float sm[16];
#pragma unroll
      for (int r = 0; r < 16; r++) {
        st[r] = fexp2(st[r]);
        sm[r] = st[r];
      }
#pragma unroll
      for (int sd = 8; sd >= 1; sd >>= 1)
#pragma unroll
        for (int r = 0; r < sd; r++) sm[r] += sm[r + sd];
      l_run[s] += sm[0] + __shfl_xor(sm[0], 32, 64);

      // P -> wave-private LDS (row=q stride 72; st[r] = P[q=ql][kv'=(r&3)+8(r>>2)+4hh])
#pragma unroll
      for (int g = 0; g < 4; g++) {
        uint2 pk;
        pk.x = pack_bf16(st[4 * g + 0], st[4 * g + 1]);
        pk.y = pack_bf16(st[4 * g + 2], st[4 * g + 3]);
        *(uint2*)(pwr + 16 * g) = pk;
      }
      // PV A-frags back (contiguous kv' convention, same as V)
      bf16x8 pa[2];
#pragma unroll
      for (int c2 = 0; c2 < 2; c2++)
        pa[c2] =
            mk8(*(const uint2*)(prd + 32 * c2), *(const uint2*)(prd + 32 * c2 + 8));

      __builtin_amdgcn_s_setprio(1);
#pragma unroll
      for (int c2 = 0; c2 < 2; c2++)
#pragma unroll
        for (int dh = 0; dh < 2; dh++)
          oacc[s][dh] = __builtin_amdgcn_mfma_f32_32x32x16_bf16(pa[c2], vf[dh][c2],
                                                                oacc[s][dh], 0, 0, 0);
      __builtin_amdgcn_s_setprio(0);
    }
    __builtin_amdgcn_s_barrier();
  }

  // ---- epilogue: reduce over kvh, then combine phases ----
  float* Os = (float*)smem;             // [2][64][64] f32 = 32KB
  float* lsc = (float*)(smem + 32768);  // [2][64]
  __syncthreads();
  if (kvh == 1) {
#pragma unroll
    for (int s = 0; s < 2; s++) {
#pragma unroll
      for (int dh = 0; dh < 2; dh++)
#pragma unroll
        for (int r = 0; r < 16; r++) {
          int q = s * 32 + (r & 3) + 8 * (r >> 2) + 4 * hh;
          Os[(p * 64 + q) * 64 + dh * 32 + ql] = oacc[s][dh][r];
        }
      lsc[p * 64 + s * 32 + ql] = l_run[s];
    }
  }
  __syncthreads();
  if (kvh == 0) {
#pragma unroll
    for (int s = 0; s < 2; s++) {
#pragma unroll
      for (int dh = 0; dh < 2; dh++)
#pragma unroll
        for (int r = 0; r < 16; r++) {
          int q = s * 32 + (r & 3) + 8 * (r >> 2) + 4 * hh;
          oacc[s][dh][r] += Os[(p * 64 + q) * 64 + dh * 32 + ql];
        }
      l_run[s] += lsc[p * 64 + s * 32 + ql];
    }
  }
  __syncthreads();
  if (kvh == 0 && p == 1) {
    float lam = __expf(lamp[h]);
    float inv[2] = {lam / l_run[0], lam / l_run[1]};
#pragma unroll
    for (int s = 0; s < 2; s++)
#pragma unroll
      for (int dh = 0; dh < 2; dh++)
#pragma unroll
        for (int r = 0; r < 16; r++) {
          int qm = (r & 3) + 8 * (r >> 2) + 4 * hh;
          float iT = __shfl(inv[s], qm, 64);
          Os[(64 + s * 32 + qm) * 64 + dh * 32 + ql] = oacc[s][dh][r] * iT;
        }
  }
  __syncthreads();
  if (kvh == 0 && p == 0) {
    float inv[2] = {1.f / l_run[0], 1.f / l_run[1]};
    u16* Og = Ob + (u64)(b * N_ + qt * 64) * C_ + h * 64;
#pragma unroll
    for (int s = 0; s < 2; s++)
#pragma unroll
      for (int dh = 0; dh < 2; dh++)
#pragma unroll
        for (int r = 0; r < 16; r++) {
          int qm = (r & 3) + 8 * (r >> 2) + 4 * hh;
          float iT = __shfl(inv[s], qm, 64);
          int q = s * 32 + qm, d = dh * 32 + ql;
          float v = oacc[s][dh][r] * iT - Os[(64 + q) * 64 + d];
          Og[(u64)q * C_ + d] = f2bf(v);
        }
  }
}

extern "C" void kernel_launch(void* const* d_in, const int* in_sizes, int n_in,
                              void* d_out, int out_size, void* d_ws, size_t ws_size,
                              hipStream_t stream) {
  const float* x = (const float*)d_in[0];
  const float* Wq = (const float*)d_in[1];
  const float* Wk = (const float*)d_in[2];
  const float* Wv = (const float*)d_in[3];
  const float* lamp = (const float*)d_in[4];
  const float* Wo = (const float*)d_in[5];
  const float* bo = (const float*)d_in[6];

  char* ws = (char*)d_ws;
  u16* xb = (u16*)ws;    ws += (u64)M_ * C_ * 2;       // x bf16 [4096][768]
  u16* wqkt = (u16*)ws;  ws += (u64)4 * C_ * C_ * 2;   // [Wq^T;Wk^T] [3072][768]
  u16* wvo = (u16*)ws;   ws += (u64)2 * C_ * C_ * 2;   // [Wv^T;Wo^T] [1536][768]
  u16* QKb = (u16*)ws;   ws += (u64)M_ * 4 * C_ * 2;   // [4096][3072]
  u16* Vt = (u16*)ws;    ws += (u64)C_ * M_ * 2;       // V^T [768][4096]
  u16* Ob = (u16*)ws;    ws += (u64)M_ * C_ * 2;       // combined [4096][768]
  u16* wvt = wvo;
  u16* wot = wvo + (u64)C_ * C_;

  k_prep<<<dim3(6528), 256, 0, stream>>>(x, Wq, Wk, Wv, Wo, xb, wqkt, wvo);
  k_gemm_qkv<<<dim3(32, 30), 256, 0, stream>>>(xb, wqkt, wvt, QKb, Vt);
  k_attn7<<<dim3(768), 256, 0, stream>>>(QKb, Vt, lamp, Ob);
  k_gemm_out<<<dim3(32, 6), 256, 0, stream>>>(Ob, wot, (float*)d_out, bo);
}